// Round 2
// baseline (2567.751 us; speedup 1.0000x reference)
//
#include <hip/hip_runtime.h>
#include <cstdint>
#include <cstddef>

// ---------------------------------------------------------------------------
// QRNN 2-bit forward, exact ternary-integer formulation. See round log.
// flags[0]=1 -> floats are f32 (else bf16); flags[1]=1 -> text is int64.
// Ternary vectors (len 1024) bit-packed as 32 u64: [2i]=plus, [2i+1]=nonzero.
// dot: both=hz&wz; neg=both&(hp^wp); k=popc(both)-2*popc(neg)
// ---------------------------------------------------------------------------

static __device__ __forceinline__ float bf2f(unsigned short b) {
  return __uint_as_float(((unsigned)b) << 16);
}
static __device__ __forceinline__ unsigned short f2bf(float f) {
  unsigned u = __float_as_uint(f);
  u = (u + 0x7FFFu + ((u >> 16) & 1u)) >> 16;  // RNE
  return (unsigned short)u;
}
static __device__ __forceinline__ float loadw(const void* p, size_t i, int isf32) {
  return isf32 ? ((const float*)p)[i] : bf2f(((const unsigned short*)p)[i]);
}

__global__ __launch_bounds__(256) void k_detect(const unsigned short* __restrict__ embu,
                                                const int* __restrict__ text,
                                                int* __restrict__ flags) {
  int i = blockIdx.x * 256 + threadIdx.x;  // 65536 u16 samples: valid in either layout
  unsigned e = (embu[i] >> 7) & 0xFFu;     // bf16-view exponent field
  unsigned long long b = __ballot(e >= 127u);
  if ((threadIdx.x & 63) == 0 && b) atomicOr(&flags[0], 1);
  if (blockIdx.x == 0 && threadIdx.x == 0) {
    int allz = 1;
    for (int j = 0; j < 32; j++)
      if (text[2 * j + 1] != 0) allz = 0;   // first 256 B: valid in either layout
    flags[1] = allz;
  }
}

__global__ __launch_bounds__(256) void k_maxabs(const void* __restrict__ w, int n,
                                                const int* __restrict__ flags,
                                                unsigned* __restrict__ out) {
  int isf32 = flags[0];
  float m = 0.f;
  int i = blockIdx.x * blockDim.x + threadIdx.x;
  int stride = gridDim.x * blockDim.x;
  for (; i < n; i += stride) m = fmaxf(m, fabsf(loadw(w, (size_t)i, isf32)));
  for (int off = 32; off > 0; off >>= 1) m = fmaxf(m, __shfl_down(m, off));
  __shared__ float red[4];
  if ((threadIdx.x & 63) == 0) red[threadIdx.x >> 6] = m;
  __syncthreads();
  if (threadIdx.x == 0) {
    float b = fmaxf(fmaxf(red[0], red[1]), fmaxf(red[2], red[3]));
    atomicMax(out, __float_as_uint(b));  // b >= 0: bit pattern order-monotone
  }
}

__global__ __launch_bounds__(1024) void k_tern_rows(
    const void* __restrict__ Wih, const void* __restrict__ Whh,
    const void* __restrict__ fcw, const int* __restrict__ flags,
    unsigned long long* __restrict__ wim, unsigned long long* __restrict__ whm,
    unsigned long long* __restrict__ fcm) {
  int isf32 = flags[0];
  int b = blockIdx.x;  // 0..4099
  const void* src;
  size_t rowoff;
  unsigned long long* dst;
  if (b < 2048)      { src = Wih; rowoff = (size_t)b * 1024; dst = wim + (size_t)b * 32; }
  else if (b < 4096) { int r = b - 2048; src = Whh; rowoff = (size_t)r * 1024; dst = whm + (size_t)r * 32; }
  else               { int r = b - 4096; src = fcw; rowoff = (size_t)r * 1024; dst = fcm + (size_t)r * 32; }
  double w = (double)loadw(src, rowoff + threadIdx.x, isf32);
  unsigned long long bp = __ballot(w > 0.05);   // THR*W_SCALE, exact f64
  unsigned long long bm = __ballot(w < -0.05);
  if ((threadIdx.x & 63) == 0) {
    int wv = threadIdx.x >> 6;
    dst[2 * wv] = bp;
    dst[2 * wv + 1] = bp | bm;
  }
}

__global__ __launch_bounds__(1024) void k_embed(const int* __restrict__ text,
    const void* __restrict__ emb, const int* __restrict__ flags,
    const unsigned* __restrict__ mab, unsigned long long* __restrict__ x0) {
  int isf32 = flags[0], i64 = flags[1];
  int bt = blockIdx.x;
  long long tok = i64 ? ((const long long*)text)[bt] : (long long)text[bt];
  double ma = (double)__uint_as_float(*mab);
  double s = exp2(ceil(log2(ma)));                 // pow-2 scale (int_max = 1)
  double w = (double)loadw(emb, (size_t)tok * 1024 + threadIdx.x, isf32);
  double q = rint(w / s);                          // half-even == jnp.round; exact div
  q = fmin(fmax(q, -2.0), 1.0);                    // clip [-2, 1] (bw = 2)
  double val = q * s;
  int code = (val > 0.5) ? 1 : ((val < -0.5) ? -1 : 0);
  unsigned long long bp = __ballot(code == 1);
  unsigned long long bm = __ballot(code == -1);
  if ((threadIdx.x & 63) == 0) {
    int wv = threadIdx.x >> 6;
    x0[(size_t)bt * 32 + 2 * wv] = bp;
    x0[(size_t)bt * 32 + 2 * wv + 1] = bp | bm;
  }
}

__global__ __launch_bounds__(256) void k_bitgemm(const unsigned long long* __restrict__ xm,
    const unsigned long long* __restrict__ wim, short* __restrict__ nbuf) {
  __shared__ __align__(16) unsigned long long lx[64 * 32];
  __shared__ unsigned any[64];
  int tid = threadIdx.x;
  int bt0 = blockIdx.x * 64;
  int r = blockIdx.y * 256 + tid;
  unsigned long long wp[16], wz[16];
  const unsigned long long* wrow = wim + (size_t)r * 32;
#pragma unroll
  for (int i = 0; i < 16; i++) { wp[i] = wrow[2 * i]; wz[i] = wrow[2 * i + 1]; }
  if (tid < 64) any[tid] = 0;
  __syncthreads();
  unsigned accor = 0;
#pragma unroll
  for (int i = 0; i < 8; i++) {
    int idx = tid * 8 + i;
    unsigned long long v = xm[(size_t)bt0 * 32 + idx];
    lx[idx] = v;
    accor |= (unsigned)(v | (v >> 32));
  }
  if (accor) atomicOr(&any[tid >> 2], 1u);
  __syncthreads();
  int lane = tid & 63;
  for (int bt = 0; bt < 64; bt++) {
    int k = 0;
    if (any[bt]) {
      uint4 m4 = ((const uint4*)(lx + (size_t)bt * 32))[lane & 15];
      int sb = 0, sn = 0;
#pragma unroll
      for (int i = 0; i < 16; i++) {
        unsigned plo = (unsigned)__builtin_amdgcn_readlane((int)m4.x, i);
        unsigned phi = (unsigned)__builtin_amdgcn_readlane((int)m4.y, i);
        unsigned zlo = (unsigned)__builtin_amdgcn_readlane((int)m4.z, i);
        unsigned zhi = (unsigned)__builtin_amdgcn_readlane((int)m4.w, i);
        unsigned long long hp = ((unsigned long long)phi << 32) | plo;
        unsigned long long hz = ((unsigned long long)zhi << 32) | zlo;
        unsigned long long both = hz & wz[i];
        unsigned long long neg = both & (hp ^ wp[i]);
        sb += __popcll(both);
        sn += __popcll(neg);
      }
      k = sb - 2 * sn;
    }
    nbuf[(size_t)(bt0 + bt) * 1024 + r] = (short)k;
  }
}

// layer: 0 or 1 — selects bias row (element offset; byte offset is dtype-dep)
__global__ __launch_bounds__(1024) void k_recur(const short* __restrict__ nbuf,
    const unsigned long long* __restrict__ whm,
    const void* __restrict__ bih, const void* __restrict__ bhh,
    const int* __restrict__ flags, int layer,
    unsigned long long* __restrict__ xout, unsigned long long* __restrict__ hidm) {
  int isf32 = flags[0];
  int b = blockIdx.x, r = threadIdx.x;
  unsigned long long wp[16], wz[16];
  const unsigned long long* wrow = whm + (size_t)r * 32;
#pragma unroll
  for (int i = 0; i < 16; i++) { wp[i] = wrow[2 * i]; wz[i] = wrow[2 * i + 1]; }
  size_t boff = (size_t)layer * 1024 + r;
  double bias = (double)loadw(bih, boff, isf32) + (double)loadw(bhh, boff, isf32);
  __shared__ __align__(16) unsigned long long H[32];
  if (r < 16) { H[2 * r] = 0; H[2 * r + 1] = 0; }
  __syncthreads();
  const short* nrow = nbuf + (size_t)b * 512 * 1024;
  unsigned long long* xrow = xout ? xout + (size_t)b * 512 * 32 : (unsigned long long*)0;
  int wv = r >> 6;
  bool l0 = (r & 63) == 0;
  int nin = (int)nrow[r];  // t = 0 preload
  for (int t = 0; t < 512; t++) {
    uint4 m4 = ((const uint4*)H)[r & 15];
    int sb = 0, sn = 0;
#pragma unroll
    for (int i = 0; i < 16; i++) {
      unsigned plo = (unsigned)__builtin_amdgcn_readlane((int)m4.x, i);
      unsigned phi = (unsigned)__builtin_amdgcn_readlane((int)m4.y, i);
      unsigned zlo = (unsigned)__builtin_amdgcn_readlane((int)m4.z, i);
      unsigned zhi = (unsigned)__builtin_amdgcn_readlane((int)m4.w, i);
      unsigned long long hp = ((unsigned long long)phi << 32) | plo;
      unsigned long long hz = ((unsigned long long)zhi << 32) | zlo;
      unsigned long long both = hz & wz[i];
      unsigned long long neg = both & (hp ^ wp[i]);
      sb += __popcll(both);
      sn += __popcll(neg);
    }
    int k = nin + sb - 2 * sn;
    double v = (double)k * 0.1 + bias;   // only rounding point; exact f64
    int code = (v > 0.5) ? 1 : ((v < -0.5) ? -1 : 0);  // tanh stage collapses
    unsigned long long bp = __ballot(code == 1);
    unsigned long long bz = __ballot(code != 0);
    int nin_next = (t < 511) ? (int)nrow[(size_t)(t + 1) * 1024 + r] : 0;
    __syncthreads();  // all reads of old H done
    if (l0) {
      H[2 * wv] = bp;
      H[2 * wv + 1] = bz;
      if (xrow) {
        xrow[t * 32 + 2 * wv] = bp;
        xrow[t * 32 + 2 * wv + 1] = bz;
      }
    }
    __syncthreads();
    nin = nin_next;
  }
  if (r < 16) {
    hidm[b * 32 + 2 * r] = H[2 * r];
    hidm[b * 32 + 2 * r + 1] = H[2 * r + 1];
  }
}

__global__ __launch_bounds__(64) void k_fc(const unsigned long long* __restrict__ hidm,
    const unsigned long long* __restrict__ fcm, const int* __restrict__ flags,
    void* __restrict__ out) {
  int isf32 = flags[0];
  int lb = blockIdx.x, lane = threadIdx.x;
  unsigned long long hp = 0, hz = 0;
  if (lane < 16) {
    hp = hidm[lb * 32 + 2 * lane];
    hz = hidm[lb * 32 + 2 * lane + 1];
  }
#pragma unroll
  for (int o = 0; o < 4; o++) {
    int k = 0;
    if (lane < 16) {
      unsigned long long wp = fcm[o * 32 + 2 * lane], wz = fcm[o * 32 + 2 * lane + 1];
      unsigned long long both = hz & wz;
      unsigned long long neg = both & (hp ^ wp);
      k = __popcll(both) - 2 * __popcll(neg);
    }
    for (int off = 8; off > 0; off >>= 1) k += __shfl_down(k, off);
    if (lane == 0) {
      float v = (float)((double)k * 0.1);
      if (isf32) ((float*)out)[lb * 4 + o] = v;
      else       ((unsigned short*)out)[lb * 4 + o] = f2bf(v);
    }
  }
}

extern "C" void kernel_launch(void* const* d_in, const int* in_sizes, int n_in,
                              void* d_out, int out_size, void* d_ws, size_t ws_size,
                              hipStream_t stream) {
  (void)in_sizes; (void)n_in; (void)out_size; (void)ws_size;
  const int* text = (const int*)d_in[0];
  // d_in[1] text_lengths: unused by the reference
  const void* emb = d_in[2];
  const void* Wih = d_in[3];
  const void* Whh = d_in[4];
  const void* bih = d_in[5];
  const void* bhh = d_in[6];
  const void* fcw = d_in[7];

  // workspace layout (~73 MB)
  char* ws = (char*)d_ws;
  size_t off = 0;
  int* flags = (int*)(ws);
  unsigned* mab = (unsigned*)(ws + 64);                      off += 256;
  unsigned long long* x0 = (unsigned long long*)(ws + off);  off += (size_t)32768 * 256;
  unsigned long long* wim = (unsigned long long*)(ws + off); off += (size_t)2048 * 256;
  unsigned long long* whm = (unsigned long long*)(ws + off); off += (size_t)2048 * 256;
  unsigned long long* fcm = (unsigned long long*)(ws + off); off += (size_t)4 * 256;
  unsigned long long* hidm = (unsigned long long*)(ws + off); off += (size_t)128 * 256;
  short* nbuf = (short*)(ws + off);                          off += (size_t)32768 * 1024 * 2;

  hipMemsetAsync(ws, 0, 256, stream);
  k_detect<<<256, 256, 0, stream>>>((const unsigned short*)emb, text, flags);
  k_maxabs<<<2048, 256, 0, stream>>>(emb, 30720000, flags, mab);
  k_tern_rows<<<4100, 1024, 0, stream>>>(Wih, Whh, fcw, flags, wim, whm, fcm);
  k_embed<<<32768, 1024, 0, stream>>>(text, emb, flags, mab, x0);
  // layer 0: x0 -> nbuf -> recurrence -> x0 (x0 dead after bitgemm)
  k_bitgemm<<<dim3(512, 4), 256, 0, stream>>>(x0, wim, nbuf);
  k_recur<<<64, 1024, 0, stream>>>(nbuf, whm, bih, bhh, flags, 0, x0, hidm);
  // layer 1
  k_bitgemm<<<dim3(512, 4), 256, 0, stream>>>(x0, wim + (size_t)1024 * 32, nbuf);
  k_recur<<<64, 1024, 0, stream>>>(nbuf, whm + (size_t)1024 * 32, bih, bhh, flags, 1,
                                   (unsigned long long*)0, hidm + 64 * 32);
  k_fc<<<128, 64, 0, stream>>>(hidm, fcm, flags, d_out);
}

// Round 3
// 2120.122 us; speedup vs baseline: 1.2111x; 1.2111x over previous
//
#include <hip/hip_runtime.h>
#include <cstdint>
#include <cstddef>

// ---------------------------------------------------------------------------
// QRNN 2-bit forward, exact ternary-integer formulation.
// flags[0]=1 -> floats are f32 (else bf16); flags[1]=1 -> text is int64.
// Ternary vectors (len 1024) bit-packed as 32 u64: [2i]=plus, [2i+1]=nonzero.
// dot: both=hz&wz; neg=both&(hp^wp); k=popc(both)-2*popc(neg)
// Decision v = k*0.1+bias vs +-0.5 is monotone in k -> precomputed integer
// thresholds kp/km reproduce the f64 predicate bit-exactly.
// ---------------------------------------------------------------------------

static __device__ __forceinline__ float bf2f(unsigned short b) {
  return __uint_as_float(((unsigned)b) << 16);
}
static __device__ __forceinline__ unsigned short f2bf(float f) {
  unsigned u = __float_as_uint(f);
  u = (u + 0x7FFFu + ((u >> 16) & 1u)) >> 16;  // RNE
  return (unsigned short)u;
}
static __device__ __forceinline__ float loadw(const void* p, size_t i, int isf32) {
  return isf32 ? ((const float*)p)[i] : bf2f(((const unsigned short*)p)[i]);
}

__global__ __launch_bounds__(256) void k_detect(const unsigned short* __restrict__ embu,
                                                const int* __restrict__ text,
                                                int* __restrict__ flags) {
  int i = blockIdx.x * 256 + threadIdx.x;  // 65536 u16 samples: valid in either layout
  unsigned e = (embu[i] >> 7) & 0xFFu;     // bf16-view exponent field
  unsigned long long b = __ballot(e >= 127u);
  if ((threadIdx.x & 63) == 0 && b) atomicOr(&flags[0], 1);
  if (blockIdx.x == 0 && threadIdx.x == 0) {
    int allz = 1;
    for (int j = 0; j < 32; j++)
      if (text[2 * j + 1] != 0) allz = 0;   // first 256 B: valid in either layout
    flags[1] = allz;
  }
}

// vectorized max|emb|: n16 = total bytes / 16
__global__ __launch_bounds__(256) void k_maxabs(const uint4* __restrict__ w,
                                                const int* __restrict__ flags,
                                                unsigned* __restrict__ out) {
  int isf32 = flags[0];
  int n16 = isf32 ? 7680000 : 3840000;  // 30720000 elems
  float mf = 0.f;
  unsigned mb = 0;
  int i = blockIdx.x * blockDim.x + threadIdx.x;
  int stride = gridDim.x * blockDim.x;
  if (isf32) {
    for (; i < n16; i += stride) {
      uint4 v = w[i];
      mf = fmaxf(mf, fabsf(__uint_as_float(v.x)));
      mf = fmaxf(mf, fabsf(__uint_as_float(v.y)));
      mf = fmaxf(mf, fabsf(__uint_as_float(v.z)));
      mf = fmaxf(mf, fabsf(__uint_as_float(v.w)));
    }
  } else {
    for (; i < n16; i += stride) {
      uint4 v = w[i];
      unsigned a;
      a = v.x & 0x7FFF7FFFu; mb = max(mb, a & 0xFFFFu); mb = max(mb, a >> 16);
      a = v.y & 0x7FFF7FFFu; mb = max(mb, a & 0xFFFFu); mb = max(mb, a >> 16);
      a = v.z & 0x7FFF7FFFu; mb = max(mb, a & 0xFFFFu); mb = max(mb, a >> 16);
      a = v.w & 0x7FFF7FFFu; mb = max(mb, a & 0xFFFFu); mb = max(mb, a >> 16);
    }
    mf = bf2f((unsigned short)mb);
  }
  for (int off = 32; off > 0; off >>= 1) mf = fmaxf(mf, __shfl_down(mf, off));
  __shared__ float red[4];
  if ((threadIdx.x & 63) == 0) red[threadIdx.x >> 6] = mf;
  __syncthreads();
  if (threadIdx.x == 0) {
    float b = fmaxf(fmaxf(red[0], red[1]), fmaxf(red[2], red[3]));
    atomicMax(out, __float_as_uint(b));  // b >= 0: bit pattern order-monotone
  }
}

__global__ __launch_bounds__(1024) void k_tern_rows(
    const void* __restrict__ Wih, const void* __restrict__ Whh,
    const void* __restrict__ fcw, const int* __restrict__ flags,
    unsigned long long* __restrict__ wim, unsigned long long* __restrict__ whm,
    unsigned long long* __restrict__ fcm) {
  int isf32 = flags[0];
  int b = blockIdx.x;  // 0..4099
  const void* src;
  size_t rowoff;
  unsigned long long* dst;
  if (b < 2048)      { src = Wih; rowoff = (size_t)b * 1024; dst = wim + (size_t)b * 32; }
  else if (b < 4096) { int r = b - 2048; src = Whh; rowoff = (size_t)r * 1024; dst = whm + (size_t)r * 32; }
  else               { int r = b - 4096; src = fcw; rowoff = (size_t)r * 1024; dst = fcm + (size_t)r * 32; }
  double w = (double)loadw(src, rowoff + threadIdx.x, isf32);
  unsigned long long bp = __ballot(w > 0.05);   // THR*W_SCALE, exact f64
  unsigned long long bm = __ballot(w < -0.05);
  if ((threadIdx.x & 63) == 0) {
    int wv = threadIdx.x >> 6;
    dst[2 * wv] = bp;
    dst[2 * wv + 1] = bp | bm;
  }
}

__global__ __launch_bounds__(1024) void k_embed(const int* __restrict__ text,
    const void* __restrict__ emb, const int* __restrict__ flags,
    const unsigned* __restrict__ mab, unsigned long long* __restrict__ x0) {
  int isf32 = flags[0], i64 = flags[1];
  int bt = blockIdx.x;
  long long tok = i64 ? ((const long long*)text)[bt] : (long long)text[bt];
  double ma = (double)__uint_as_float(*mab);
  float s = (float)exp2(ceil(log2(ma)));           // pow-2 scale (int_max = 1)
  float inv_s = 1.0f / s;                          // exact (pow-2)
  float w = loadw(emb, (size_t)tok * 1024 + threadIdx.x, isf32);
  float q = rintf(w * inv_s);                      // exact: w*inv_s exact, half-even
  q = fminf(fmaxf(q, -2.0f), 1.0f);                // clip [-2, 1] (bw = 2)
  float val = q * s;                               // exact
  int code = (val > 0.5f) ? 1 : ((val < -0.5f) ? -1 : 0);
  unsigned long long bp = __ballot(code == 1);
  unsigned long long bm = __ballot(code == -1);
  if ((threadIdx.x & 63) == 0) {
    int wv = threadIdx.x >> 6;
    x0[(size_t)bt * 32 + 2 * wv] = bp;
    x0[(size_t)bt * 32 + 2 * wv + 1] = bp | bm;
  }
}

__global__ __launch_bounds__(256) void k_bitgemm(const unsigned long long* __restrict__ xm,
    const unsigned long long* __restrict__ wim, short* __restrict__ nbuf) {
  __shared__ __align__(16) unsigned long long lx[64 * 32];
  __shared__ unsigned any[64];
  int tid = threadIdx.x;
  int bt0 = blockIdx.x * 64;
  int r = blockIdx.y * 256 + tid;
  unsigned long long wp[16], wz[16];
  const unsigned long long* wrow = wim + (size_t)r * 32;
#pragma unroll
  for (int i = 0; i < 16; i++) { wp[i] = wrow[2 * i]; wz[i] = wrow[2 * i + 1]; }
  if (tid < 64) any[tid] = 0;
  __syncthreads();
  unsigned accor = 0;
#pragma unroll
  for (int i = 0; i < 8; i++) {
    int idx = tid * 8 + i;
    unsigned long long v = xm[(size_t)bt0 * 32 + idx];
    lx[idx] = v;
    accor |= (unsigned)(v | (v >> 32));
  }
  if (accor) atomicOr(&any[tid >> 2], 1u);
  __syncthreads();
  int lane = tid & 63;
  for (int bt = 0; bt < 64; bt++) {
    int k = 0;
    if (any[bt]) {
      uint4 m4 = ((const uint4*)(lx + (size_t)bt * 32))[lane & 15];
      int sb = 0, sn = 0;
#pragma unroll
      for (int i = 0; i < 16; i++) {
        unsigned plo = (unsigned)__builtin_amdgcn_readlane((int)m4.x, i);
        unsigned phi = (unsigned)__builtin_amdgcn_readlane((int)m4.y, i);
        unsigned zlo = (unsigned)__builtin_amdgcn_readlane((int)m4.z, i);
        unsigned zhi = (unsigned)__builtin_amdgcn_readlane((int)m4.w, i);
        unsigned long long hp = ((unsigned long long)phi << 32) | plo;
        unsigned long long hz = ((unsigned long long)zhi << 32) | zlo;
        unsigned long long both = hz & wz[i];
        unsigned long long neg = both & (hp ^ wp[i]);
        sb += __popcll(both);
        sn += __popcll(neg);
      }
      k = sb - 2 * sn;
    }
    nbuf[(size_t)(bt0 + bt) * 1024 + r] = (short)k;
  }
}

// ---- persistent recurrence ------------------------------------------------
// One block per batch; thread = output row. Per step:
//   - H broadcast via 16 same-address ds_read_b128 (LDS pipe, conflict-free)
//   - integer-threshold decision (no f64 in the loop)
//   - single barrier (double-buffered H)
__global__ __launch_bounds__(1024) void k_recur(const short* __restrict__ nbuf,
    const unsigned long long* __restrict__ whm,
    const void* __restrict__ bih, const void* __restrict__ bhh,
    const int* __restrict__ flags, int layer,
    unsigned long long* __restrict__ xout, unsigned long long* __restrict__ hidm) {
  int isf32 = flags[0];
  int b = blockIdx.x, r = threadIdx.x;
  unsigned wplo[16], wphi[16], wzlo[16], wzhi[16];
  const uint4* wrow = (const uint4*)(whm + (size_t)r * 32);  // uint4 i = (plus_i, nz_i)
#pragma unroll
  for (int i = 0; i < 16; i++) {
    uint4 w4 = wrow[i];
    wplo[i] = w4.x; wphi[i] = w4.y; wzlo[i] = w4.z; wzhi[i] = w4.w;
  }
  size_t boff = (size_t)layer * 1024 + r;
  double bias = (double)loadw(bih, boff, isf32) + (double)loadw(bhh, boff, isf32);
  // exact integer thresholds: kp = min{k: k*0.1+bias > 0.5}, km = max{k: < -0.5}
  int kp = (int)ceil((0.5 - bias) * 10.0);
  while ((double)kp * 0.1 + bias <= 0.5) kp++;
  while ((double)(kp - 1) * 0.1 + bias > 0.5) kp--;
  int km = (int)floor((-0.5 - bias) * 10.0);
  while ((double)km * 0.1 + bias >= -0.5) km--;
  while ((double)(km + 1) * 0.1 + bias < -0.5) km++;

  __shared__ __align__(16) uint4 Hbuf[2][16];  // [buf][pair]: .xy=plus, .zw=nonzero
  if (r < 32) ((unsigned long long*)Hbuf)[r] = 0;  // zero buffer 0
  __syncthreads();
  const short* nrow = nbuf + (size_t)b * 512 * 1024 + r;
  unsigned long long* xrow = xout ? xout + (size_t)b * 512 * 32 : (unsigned long long*)0;
  int wv = r >> 6;
  bool l0 = (r & 63) == 0;
  int nin = (int)nrow[0];  // t = 0 preload
  int pb = 0;
  for (int t = 0; t < 512; t++) {
    const uint4* Hq = Hbuf[pb];
    int sb = 0, sn = 0;
#pragma unroll
    for (int i = 0; i < 16; i++) {
      uint4 h = Hq[i];  // broadcast ds_read_b128
      unsigned blo = h.z & wzlo[i];
      unsigned bhi = h.w & wzhi[i];
      unsigned nlo = (h.x ^ wplo[i]) & blo;
      unsigned nhi = (h.y ^ wphi[i]) & bhi;
      sb += __popc(blo) + __popc(bhi);
      sn += __popc(nlo) + __popc(nhi);
    }
    int k = nin + sb - 2 * sn;
    int nin_next = (t < 511) ? (int)nrow[(size_t)(t + 1) * 1024] : 0;  // prefetch
    unsigned long long bp = __ballot(k >= kp);
    unsigned long long bm = __ballot(k <= km);
    unsigned long long bz = bp | bm;
    if (l0) {
      uint4 o;
      o.x = (unsigned)bp; o.y = (unsigned)(bp >> 32);
      o.z = (unsigned)bz; o.w = (unsigned)(bz >> 32);
      Hbuf[pb ^ 1][wv] = o;
      if (xrow) ((uint4*)(xrow + (size_t)t * 32))[wv] = o;
    }
    __syncthreads();  // writes of Hbuf[pb^1] visible; reads of Hbuf[pb] done
    pb ^= 1;
    nin = nin_next;
  }
  if (r < 16) {  // final h is in Hbuf[pb]
    uint4 h = Hbuf[pb][r];
    hidm[b * 32 + 2 * r]     = ((unsigned long long)h.y << 32) | h.x;
    hidm[b * 32 + 2 * r + 1] = ((unsigned long long)h.w << 32) | h.z;
  }
}

__global__ __launch_bounds__(64) void k_fc(const unsigned long long* __restrict__ hidm,
    const unsigned long long* __restrict__ fcm, const int* __restrict__ flags,
    void* __restrict__ out) {
  int isf32 = flags[0];
  int lb = blockIdx.x, lane = threadIdx.x;
  unsigned long long hp = 0, hz = 0;
  if (lane < 16) {
    hp = hidm[lb * 32 + 2 * lane];
    hz = hidm[lb * 32 + 2 * lane + 1];
  }
#pragma unroll
  for (int o = 0; o < 4; o++) {
    int k = 0;
    if (lane < 16) {
      unsigned long long wp = fcm[o * 32 + 2 * lane], wz = fcm[o * 32 + 2 * lane + 1];
      unsigned long long both = hz & wz;
      unsigned long long neg = both & (hp ^ wp);
      k = __popcll(both) - 2 * __popcll(neg);
    }
    for (int off = 8; off > 0; off >>= 1) k += __shfl_down(k, off);
    if (lane == 0) {
      float v = (float)((double)k * 0.1);
      if (isf32) ((float*)out)[lb * 4 + o] = v;
      else       ((unsigned short*)out)[lb * 4 + o] = f2bf(v);
    }
  }
}

extern "C" void kernel_launch(void* const* d_in, const int* in_sizes, int n_in,
                              void* d_out, int out_size, void* d_ws, size_t ws_size,
                              hipStream_t stream) {
  (void)in_sizes; (void)n_in; (void)out_size; (void)ws_size;
  const int* text = (const int*)d_in[0];
  // d_in[1] text_lengths: unused by the reference
  const void* emb = d_in[2];
  const void* Wih = d_in[3];
  const void* Whh = d_in[4];
  const void* bih = d_in[5];
  const void* bhh = d_in[6];
  const void* fcw = d_in[7];

  // workspace layout (~73 MB)
  char* ws = (char*)d_ws;
  size_t off = 0;
  int* flags = (int*)(ws);
  unsigned* mab = (unsigned*)(ws + 64);                      off += 256;
  unsigned long long* x0 = (unsigned long long*)(ws + off);  off += (size_t)32768 * 256;
  unsigned long long* wim = (unsigned long long*)(ws + off); off += (size_t)2048 * 256;
  unsigned long long* whm = (unsigned long long*)(ws + off); off += (size_t)2048 * 256;
  unsigned long long* fcm = (unsigned long long*)(ws + off); off += (size_t)4 * 256;
  unsigned long long* hidm = (unsigned long long*)(ws + off); off += (size_t)128 * 256;
  short* nbuf = (short*)(ws + off);                          off += (size_t)32768 * 1024 * 2;

  hipMemsetAsync(ws, 0, 256, stream);
  k_detect<<<256, 256, 0, stream>>>((const unsigned short*)emb, text, flags);
  k_maxabs<<<2048, 256, 0, stream>>>((const uint4*)emb, flags, mab);
  k_tern_rows<<<4100, 1024, 0, stream>>>(Wih, Whh, fcw, flags, wim, whm, fcm);
  k_embed<<<32768, 1024, 0, stream>>>(text, emb, flags, mab, x0);
  // layer 0: x0 -> nbuf -> recurrence -> x0 (x0 dead after bitgemm)
  k_bitgemm<<<dim3(512, 4), 256, 0, stream>>>(x0, wim, nbuf);
  k_recur<<<64, 1024, 0, stream>>>(nbuf, whm, bih, bhh, flags, 0, x0, hidm);
  // layer 1
  k_bitgemm<<<dim3(512, 4), 256, 0, stream>>>(x0, wim + (size_t)1024 * 32, nbuf);
  k_recur<<<64, 1024, 0, stream>>>(nbuf, whm + (size_t)1024 * 32, bih, bhh, flags, 1,
                                   (unsigned long long*)0, hidm + 64 * 32);
  k_fc<<<128, 64, 0, stream>>>(hidm, fcm, flags, d_out);
}

// Round 4
// 2081.698 us; speedup vs baseline: 1.2335x; 1.0185x over previous
//
#include <hip/hip_runtime.h>
#include <cstdint>
#include <cstddef>

// ---------------------------------------------------------------------------
// QRNN 2-bit forward, exact ternary-integer formulation.
// flags[0]=1 -> floats are f32 (else bf16); flags[1]=1 -> text is int64.
// Ternary vectors (len 1024) bit-packed as 32 u64: [2i]=plus, [2i+1]=nonzero.
// As uint4 i: (p.lo, p.hi, z.lo, z.hi) for elements 64i..64i+63.
// dot: both=hz&wz; neg=both&(hp^wp); k=popc(both)-2*popc(neg)
// Decision v = k*0.1+bias vs +-0.5 is monotone in k -> precomputed integer
// thresholds kp/km reproduce the f64 predicate bit-exactly.
//
// k_recur design: weights live in VGPRs (64 VGPR/thread x 1024 threads =
// 256 KB/CU — only the RF is big enough); h broadcast via same-address
// ds_read_b128 (conflict-free). __launch_bounds__(1024,4) => 1 block/CU =>
// 128-VGPR cap: REQUIRED to avoid spilling the 64 weight VGPRs (R3 ran at
// VGPR_Count=48 => spilled => ~2x step-time).
// ---------------------------------------------------------------------------

static __device__ __forceinline__ float bf2f(unsigned short b) {
  return __uint_as_float(((unsigned)b) << 16);
}
static __device__ __forceinline__ unsigned short f2bf(float f) {
  unsigned u = __float_as_uint(f);
  u = (u + 0x7FFFu + ((u >> 16) & 1u)) >> 16;  // RNE
  return (unsigned short)u;
}
static __device__ __forceinline__ float loadw(const void* p, size_t i, int isf32) {
  return isf32 ? ((const float*)p)[i] : bf2f(((const unsigned short*)p)[i]);
}

__global__ __launch_bounds__(256) void k_detect(const unsigned short* __restrict__ embu,
                                                const int* __restrict__ text,
                                                int* __restrict__ flags) {
  int i = blockIdx.x * 256 + threadIdx.x;  // 65536 u16 samples: valid in either layout
  unsigned e = (embu[i] >> 7) & 0xFFu;     // bf16-view exponent field
  unsigned long long b = __ballot(e >= 127u);
  if ((threadIdx.x & 63) == 0 && b) atomicOr(&flags[0], 1);
  if (blockIdx.x == 0 && threadIdx.x == 0) {
    int allz = 1;
    for (int j = 0; j < 32; j++)
      if (text[2 * j + 1] != 0) allz = 0;   // first 256 B: valid in either layout
    flags[1] = allz;
  }
}

// vectorized max|emb|
__global__ __launch_bounds__(256) void k_maxabs(const uint4* __restrict__ w,
                                                const int* __restrict__ flags,
                                                unsigned* __restrict__ out) {
  int isf32 = flags[0];
  int n16 = isf32 ? 7680000 : 3840000;  // 30720000 elems / (4 or 8 per uint4)
  float mf = 0.f;
  unsigned mb = 0;
  int i = blockIdx.x * blockDim.x + threadIdx.x;
  int stride = gridDim.x * blockDim.x;
  if (isf32) {
    for (; i < n16; i += stride) {
      uint4 v = w[i];
      mf = fmaxf(mf, fabsf(__uint_as_float(v.x)));
      mf = fmaxf(mf, fabsf(__uint_as_float(v.y)));
      mf = fmaxf(mf, fabsf(__uint_as_float(v.z)));
      mf = fmaxf(mf, fabsf(__uint_as_float(v.w)));
    }
  } else {
    for (; i < n16; i += stride) {
      uint4 v = w[i];
      unsigned a;
      a = v.x & 0x7FFF7FFFu; mb = max(mb, a & 0xFFFFu); mb = max(mb, a >> 16);
      a = v.y & 0x7FFF7FFFu; mb = max(mb, a & 0xFFFFu); mb = max(mb, a >> 16);
      a = v.z & 0x7FFF7FFFu; mb = max(mb, a & 0xFFFFu); mb = max(mb, a >> 16);
      a = v.w & 0x7FFF7FFFu; mb = max(mb, a & 0xFFFFu); mb = max(mb, a >> 16);
    }
    mf = bf2f((unsigned short)mb);
  }
  for (int off = 32; off > 0; off >>= 1) mf = fmaxf(mf, __shfl_down(mf, off));
  __shared__ float red[4];
  if ((threadIdx.x & 63) == 0) red[threadIdx.x >> 6] = mf;
  __syncthreads();
  if (threadIdx.x == 0) {
    float b = fmaxf(fmaxf(red[0], red[1]), fmaxf(red[2], red[3]));
    atomicMax(out, __float_as_uint(b));  // b >= 0: bit pattern order-monotone
  }
}

__global__ __launch_bounds__(1024) void k_tern_rows(
    const void* __restrict__ Wih, const void* __restrict__ Whh,
    const void* __restrict__ fcw, const int* __restrict__ flags,
    unsigned long long* __restrict__ wim, unsigned long long* __restrict__ whm,
    unsigned long long* __restrict__ fcm) {
  int isf32 = flags[0];
  int b = blockIdx.x;  // 0..4099
  const void* src;
  size_t rowoff;
  unsigned long long* dst;
  if (b < 2048)      { src = Wih; rowoff = (size_t)b * 1024; dst = wim + (size_t)b * 32; }
  else if (b < 4096) { int r = b - 2048; src = Whh; rowoff = (size_t)r * 1024; dst = whm + (size_t)r * 32; }
  else               { int r = b - 4096; src = fcw; rowoff = (size_t)r * 1024; dst = fcm + (size_t)r * 32; }
  double w = (double)loadw(src, rowoff + threadIdx.x, isf32);
  unsigned long long bp = __ballot(w > 0.05);   // THR*W_SCALE, exact f64
  unsigned long long bm = __ballot(w < -0.05);
  if ((threadIdx.x & 63) == 0) {
    int wv = threadIdx.x >> 6;
    dst[2 * wv] = bp;
    dst[2 * wv + 1] = bp | bm;
  }
}

__global__ __launch_bounds__(1024) void k_embed(const int* __restrict__ text,
    const void* __restrict__ emb, const int* __restrict__ flags,
    const unsigned* __restrict__ mab, unsigned long long* __restrict__ x0) {
  int isf32 = flags[0], i64 = flags[1];
  int bt = blockIdx.x;
  long long tok = i64 ? ((const long long*)text)[bt] : (long long)text[bt];
  double ma = (double)__uint_as_float(*mab);
  float s = (float)exp2(ceil(log2(ma)));           // pow-2 scale (int_max = 1)
  float inv_s = 1.0f / s;                          // exact (pow-2)
  float w = loadw(emb, (size_t)tok * 1024 + threadIdx.x, isf32);
  float q = rintf(w * inv_s);                      // exact mul, half-even
  q = fminf(fmaxf(q, -2.0f), 1.0f);                // clip [-2, 1] (bw = 2)
  float val = q * s;                               // exact
  int code = (val > 0.5f) ? 1 : ((val < -0.5f) ? -1 : 0);
  unsigned long long bp = __ballot(code == 1);
  unsigned long long bm = __ballot(code == -1);
  if ((threadIdx.x & 63) == 0) {
    int wv = threadIdx.x >> 6;
    x0[(size_t)bt * 32 + 2 * wv] = bp;
    x0[(size_t)bt * 32 + 2 * wv + 1] = bp | bm;
  }
}

// ---- bit-GEMM: n[bt][r] = <x_row[bt], Wi_row[r]> (integer) ----------------
// 64 bt-rows x 256 r-cols per block. x rows broadcast from LDS (same-address
// uint4 reads, conflict-free). Weights in VGPRs: (256,4) => 128-VGPR cap.
__global__ __launch_bounds__(256, 4) void k_bitgemm(const unsigned long long* __restrict__ xm,
    const unsigned long long* __restrict__ wim, short* __restrict__ nbuf) {
  __shared__ __align__(16) uint4 lx[64 * 16];  // [bt][i] = (p.lo,p.hi,z.lo,z.hi)
  __shared__ unsigned any[64];
  int tid = threadIdx.x;
  int bt0 = blockIdx.x * 64;
  int r = blockIdx.y * 256 + tid;
  unsigned wplo[16], wphi[16], wzlo[16], wzhi[16];
  const uint4* wrow = (const uint4*)(wim + (size_t)r * 32);
#pragma unroll
  for (int i = 0; i < 16; i++) {
    uint4 w4 = wrow[i];
    wplo[i] = w4.x; wphi[i] = w4.y; wzlo[i] = w4.z; wzhi[i] = w4.w;
  }
  if (tid < 64) any[tid] = 0;
  __syncthreads();
  unsigned accor = 0;
#pragma unroll
  for (int i = 0; i < 4; i++) {
    int idx = tid * 4 + i;  // 0..1023 uint4 slots, straight copy
    uint4 v = ((const uint4*)(xm + (size_t)bt0 * 32))[idx];
    lx[idx] = v;
    accor |= v.z | v.w;  // nonzero-mask halves
  }
  if (accor) atomicOr(&any[tid >> 2], 1u);  // 4 threads per bt row
  __syncthreads();
  for (int bt = 0; bt < 64; bt++) {
    int k = 0;
    if (any[bt]) {
      const uint4* hx = lx + bt * 16;
      int sb = 0, sn = 0;
#pragma unroll
      for (int i = 0; i < 16; i++) {
        uint4 h = hx[i];  // broadcast ds_read_b128
        unsigned blo = h.z & wzlo[i];
        unsigned bhi = h.w & wzhi[i];
        unsigned nlo = (h.x ^ wplo[i]) & blo;
        unsigned nhi = (h.y ^ wphi[i]) & bhi;
        sb += __popc(blo) + __popc(bhi);
        sn += __popc(nlo) + __popc(nhi);
      }
      k = sb - 2 * sn;
    }
    nbuf[(size_t)(bt0 + bt) * 1024 + r] = (short)k;
  }
}

// ---- persistent recurrence ------------------------------------------------
// One block per batch; thread = output row. (1024,4): 1 block/CU, 128-VGPR
// cap so the 64 weight VGPRs stay resident (no spill).
__global__ __launch_bounds__(1024, 4) void k_recur(const short* __restrict__ nbuf,
    const unsigned long long* __restrict__ whm,
    const void* __restrict__ bih, const void* __restrict__ bhh,
    const int* __restrict__ flags, int layer,
    unsigned long long* __restrict__ xout, unsigned long long* __restrict__ hidm) {
  int isf32 = flags[0];
  int b = blockIdx.x, r = threadIdx.x;
  unsigned wplo[16], wphi[16], wzlo[16], wzhi[16];
  const uint4* wrow = (const uint4*)(whm + (size_t)r * 32);
#pragma unroll
  for (int i = 0; i < 16; i++) {
    uint4 w4 = wrow[i];
    wplo[i] = w4.x; wphi[i] = w4.y; wzlo[i] = w4.z; wzhi[i] = w4.w;
  }
  size_t boff = (size_t)layer * 1024 + r;
  double bias = (double)loadw(bih, boff, isf32) + (double)loadw(bhh, boff, isf32);
  // exact integer thresholds reproducing the f64 predicate
  int kp = (int)ceil((0.5 - bias) * 10.0);
  while ((double)kp * 0.1 + bias <= 0.5) kp++;
  while ((double)(kp - 1) * 0.1 + bias > 0.5) kp--;
  int km = (int)floor((-0.5 - bias) * 10.0);
  while ((double)km * 0.1 + bias >= -0.5) km--;
  while ((double)(km + 1) * 0.1 + bias < -0.5) km++;

  __shared__ __align__(16) uint4 Hbuf[2][16];  // (p.lo,p.hi,z.lo,z.hi)
  if (r < 32) ((unsigned long long*)Hbuf)[r] = 0;  // zero buffer 0
  __syncthreads();
  const short* nrow = nbuf + (size_t)b * 512 * 1024 + r;
  unsigned long long* xrow = xout ? xout + (size_t)b * 512 * 32 : (unsigned long long*)0;
  int wv = r >> 6;
  bool l0 = (r & 63) == 0;
  int nin = (int)nrow[0];  // t = 0 preload
  int pb = 0;
  for (int t = 0; t < 512; t++) {
    const uint4* Hq = Hbuf[pb];
    int sb = 0, sn = 0;
#pragma unroll
    for (int i = 0; i < 16; i++) {
      uint4 h = Hq[i];  // broadcast ds_read_b128
      unsigned blo = h.z & wzlo[i];
      unsigned bhi = h.w & wzhi[i];
      unsigned nlo = (h.x ^ wplo[i]) & blo;
      unsigned nhi = (h.y ^ wphi[i]) & bhi;
      sb += __popc(blo) + __popc(bhi);
      sn += __popc(nlo) + __popc(nhi);
    }
    int k = nin + sb - 2 * sn;
    int nin_next = (t < 511) ? (int)nrow[(size_t)(t + 1) * 1024] : 0;  // prefetch
    unsigned long long bp = __ballot(k >= kp);
    unsigned long long bm = __ballot(k <= km);
    unsigned long long bz = bp | bm;
    if (l0) {
      uint4 o;
      o.x = (unsigned)bp; o.y = (unsigned)(bp >> 32);
      o.z = (unsigned)bz; o.w = (unsigned)(bz >> 32);
      Hbuf[pb ^ 1][wv] = o;
      if (xrow) ((uint4*)(xrow + (size_t)t * 32))[wv] = o;
    }
    __syncthreads();  // writes of Hbuf[pb^1] visible; reads of Hbuf[pb] done
    pb ^= 1;
    nin = nin_next;
  }
  if (r < 16) {  // final h is in Hbuf[pb]
    uint4 h = Hbuf[pb][r];
    hidm[b * 32 + 2 * r]     = ((unsigned long long)h.y << 32) | h.x;
    hidm[b * 32 + 2 * r + 1] = ((unsigned long long)h.w << 32) | h.z;
  }
}

__global__ __launch_bounds__(64) void k_fc(const unsigned long long* __restrict__ hidm,
    const unsigned long long* __restrict__ fcm, const int* __restrict__ flags,
    void* __restrict__ out) {
  int isf32 = flags[0];
  int lb = blockIdx.x, lane = threadIdx.x;
  unsigned long long hp = 0, hz = 0;
  if (lane < 16) {
    hp = hidm[lb * 32 + 2 * lane];
    hz = hidm[lb * 32 + 2 * lane + 1];
  }
#pragma unroll
  for (int o = 0; o < 4; o++) {
    int k = 0;
    if (lane < 16) {
      unsigned long long wp = fcm[o * 32 + 2 * lane], wz = fcm[o * 32 + 2 * lane + 1];
      unsigned long long both = hz & wz;
      unsigned long long neg = both & (hp ^ wp);
      k = __popcll(both) - 2 * __popcll(neg);
    }
    for (int off = 8; off > 0; off >>= 1) k += __shfl_down(k, off);
    if (lane == 0) {
      float v = (float)((double)k * 0.1);
      if (isf32) ((float*)out)[lb * 4 + o] = v;
      else       ((unsigned short*)out)[lb * 4 + o] = f2bf(v);
    }
  }
}

extern "C" void kernel_launch(void* const* d_in, const int* in_sizes, int n_in,
                              void* d_out, int out_size, void* d_ws, size_t ws_size,
                              hipStream_t stream) {
  (void)in_sizes; (void)n_in; (void)out_size; (void)ws_size;
  const int* text = (const int*)d_in[0];
  // d_in[1] text_lengths: unused by the reference
  const void* emb = d_in[2];
  const void* Wih = d_in[3];
  const void* Whh = d_in[4];
  const void* bih = d_in[5];
  const void* bhh = d_in[6];
  const void* fcw = d_in[7];

  // workspace layout (~73 MB)
  char* ws = (char*)d_ws;
  size_t off = 0;
  int* flags = (int*)(ws);
  unsigned* mab = (unsigned*)(ws + 64);                      off += 256;
  unsigned long long* x0 = (unsigned long long*)(ws + off);  off += (size_t)32768 * 256;
  unsigned long long* wim = (unsigned long long*)(ws + off); off += (size_t)2048 * 256;
  unsigned long long* whm = (unsigned long long*)(ws + off); off += (size_t)2048 * 256;
  unsigned long long* fcm = (unsigned long long*)(ws + off); off += (size_t)4 * 256;
  unsigned long long* hidm = (unsigned long long*)(ws + off); off += (size_t)128 * 256;
  short* nbuf = (short*)(ws + off);                          off += (size_t)32768 * 1024 * 2;

  hipMemsetAsync(ws, 0, 256, stream);
  k_detect<<<256, 256, 0, stream>>>((const unsigned short*)emb, text, flags);
  k_maxabs<<<2048, 256, 0, stream>>>((const uint4*)emb, flags, mab);
  k_tern_rows<<<4100, 1024, 0, stream>>>(Wih, Whh, fcw, flags, wim, whm, fcm);
  k_embed<<<32768, 1024, 0, stream>>>(text, emb, flags, mab, x0);
  // layer 0: x0 -> nbuf -> recurrence -> x0 (x0 dead after bitgemm)
  k_bitgemm<<<dim3(512, 4), 256, 0, stream>>>(x0, wim, nbuf);
  k_recur<<<64, 1024, 0, stream>>>(nbuf, whm, bih, bhh, flags, 0, x0, hidm);
  // layer 1
  k_bitgemm<<<dim3(512, 4), 256, 0, stream>>>(x0, wim + (size_t)1024 * 32, nbuf);
  k_recur<<<64, 1024, 0, stream>>>(nbuf, whm + (size_t)1024 * 32, bih, bhh, flags, 1,
                                   (unsigned long long*)0, hidm + 64 * 32);
  k_fc<<<128, 64, 0, stream>>>(hidm, fcm, flags, d_out);
}